// Round 5
// baseline (25.013 us; speedup 1.0000x reference)
//
#include <hip/hip_runtime.h>

#define KS   7
#define KK   49
#define MIDJ 24
#define H    256
#define W    320
#define HW   (H * W)
#define BS   4
#define ITERS 6

typedef float vfloat2 __attribute__((ext_vector_type(2)));

// R4 = R3 with clang ext_vector types for the nontemporal builtins.
// kern (64 MB), att (5 MB), input0, out touched exactly once per pixel ->
// nt flag (no cache allocation) to test the L3-hit-path-plateau theory.
// input (7x7 neighborhood, ~49x reuse) stays on the cached path.
__global__ __launch_bounds__(256) void dyspn_kernel(
    const float* __restrict__ kern,    // (BS, KK, HW)
    const float* __restrict__ input,   // (BS, 1, H, W)
    const float* __restrict__ input0,  // (BS, 1, H, W)
    const float* __restrict__ att,     // (BS, ITERS, 4, HW)
    const int*   __restrict__ i_ptr,   // scalar
    float*       __restrict__ out)     // (BS, 1, H, W)
{
    const int i_sel = *i_ptr;

    int t   = blockIdx.x * blockDim.x + threadIdx.x;  // 2 pixels per thread
    int idx = t * 2;
    if (idx >= BS * HW) return;

    int b = idx / HW;
    int p = idx - b * HW;          // even
    int y = p / W;
    int x = p - y * W;

    // attention[b, i_sel, r, p..p+1]  (streamed, nt)
    const float* attb = att + ((size_t)(b * ITERS + i_sel)) * 4 * HW + p;
    vfloat2 a0 = __builtin_nontemporal_load((const vfloat2*)(attb));
    vfloat2 a1 = __builtin_nontemporal_load((const vfloat2*)(attb + HW));
    vfloat2 a2 = __builtin_nontemporal_load((const vfloat2*)(attb + 2 * HW));
    vfloat2 a3 = __builtin_nontemporal_load((const vfloat2*)(attb + 3 * HW));
    const float ar0[4] = {a0.x, a1.x, a2.x, a3.x};
    const float ar1[4] = {a0.y, a1.y, a2.y, a3.y};

    const float* kb  = kern + (size_t)b * KK * HW + p;
    const float* inb = input + (size_t)b * HW;

    vfloat2 mid2 = __builtin_nontemporal_load((const vfloat2*)(input0 + (size_t)b * HW + p));

    float acc0 = 0.f, acc1 = 0.f, den0 = 0.f, den1 = 0.f;

#pragma unroll
    for (int j = 0; j < KK; ++j) {
        const int dy = j / KS - 3;                       // compile-time
        const int dx = j % KS - 3;                       // compile-time
        const int r  = max(dy < 0 ? -dy : dy,
                           dx < 0 ? -dx : dx);           // ring id, compile-time

        vfloat2 kv = __builtin_nontemporal_load((const vfloat2*)(kb + (size_t)j * HW));
        float v0 = kv.x * ar0[r];
        float v1 = kv.y * ar1[r];
        den0 += fabsf(v0);
        den1 += fabsf(v1);

        float p0, p1;
        if (j == MIDJ) {
            p0 = mid2.x; p1 = mid2.y;
        } else {
            const int yy = y + dy;
            if (yy >= 0 && yy < H) {
                const int x0 = x + dx;
                const int x1 = x0 + 1;
                const float* row = inb + yy * W;          // cached path (reused)
                p0 = (x0 >= 0 && x0 < W) ? row[x0] : 0.f;
                p1 = (x1 >= 0 && x1 < W) ? row[x1] : 0.f;
            } else {
                p0 = 0.f; p1 = 0.f;
            }
        }
        acc0 = fmaf(v0, p0, acc0);
        acc1 = fmaf(v1, p1, acc1);
    }

    vfloat2 o;
    o.x = acc0 / den0;
    o.y = acc1 / den1;
    __builtin_nontemporal_store(o, (vfloat2*)(out + (size_t)b * HW + p));
}

extern "C" void kernel_launch(void* const* d_in, const int* in_sizes, int n_in,
                              void* d_out, int out_size, void* d_ws, size_t ws_size,
                              hipStream_t stream) {
    const float* kern   = (const float*)d_in[0];
    const float* input  = (const float*)d_in[1];
    const float* input0 = (const float*)d_in[2];
    const float* att    = (const float*)d_in[3];
    const int*   i_ptr  = (const int*)d_in[4];
    float* out = (float*)d_out;

    const int total_threads = BS * HW / 2;   // 163840
    const int block = 256;
    const int grid  = (total_threads + block - 1) / block;  // 640

    dyspn_kernel<<<grid, block, 0, stream>>>(kern, input, input0, att, i_ptr, out);
}